// Round 5
// baseline (501.185 us; speedup 1.0000x reference)
//
#include <hip/hip_runtime.h>

// ---- types / helpers -------------------------------------------------------
typedef __bf16 bf16x8 __attribute__((ext_vector_type(8)));
typedef __bf16 bf16x4 __attribute__((ext_vector_type(4)));
typedef __bf16 bf16x2 __attribute__((ext_vector_type(2)));
typedef float f32x4 __attribute__((ext_vector_type(4)));
typedef float f32x16 __attribute__((ext_vector_type(16)));
typedef unsigned short ushortx8 __attribute__((ext_vector_type(8)));
typedef unsigned short ushortx4 __attribute__((ext_vector_type(4)));
typedef unsigned int uint32x4v __attribute__((ext_vector_type(4)));

#define DEVI static __device__ __forceinline__

DEVI unsigned short f2bf(float f) {  // round-to-nearest-even f32 -> bf16
  unsigned int u = __builtin_bit_cast(unsigned int, f);
  u += 0x7FFFu + ((u >> 16) & 1u);
  return (unsigned short)(u >> 16);
}

DEVI bf16x8 ld8(const unsigned short* p) {  // 16B vector load (global or LDS)
  return __builtin_bit_cast(bf16x8, *(const ushortx8*)p);
}

DEVI void gll16(const unsigned short* g, unsigned short* l) {  // global->LDS 16B DMA
  __builtin_amdgcn_global_load_lds((const __attribute__((address_space(1))) void*)g,
                                   (__attribute__((address_space(3))) void*)l, 16, 0, 0);
}

#define MFMA16(a, b, c) __builtin_amdgcn_mfma_f32_16x16x32_bf16(a, b, c, 0, 0, 0)
#define MFMA32(a, b, c) __builtin_amdgcn_mfma_f32_32x32x16_bf16(a, b, c, 0, 0, 0)

DEVI unsigned pkbf(float lo, float hi) {  // pack 2 f32 -> u32 of 2 bf16 (lo in low16)
  bf16x2 v;
  v[0] = (__bf16)lo;
  v[1] = (__bf16)hi;
  return __builtin_bit_cast(unsigned, v);
}

DEVI float swaphalf_max(float x) {  // max(own, other-32-lane-half) for all lanes
  unsigned xu = __builtin_bit_cast(unsigned, x);
  auto pr = __builtin_amdgcn_permlane32_swap(xu, xu, false, false);
  return fmaxf(__builtin_bit_cast(float, (unsigned)pr[0]),
               __builtin_bit_cast(float, (unsigned)pr[1]));
}

// ---- problem constants -----------------------------------------------------
// B=4, T=2048, E=1024, H=16, D=64
#define SB 4
#define ST 2048
#define SE 1024
#define SH 16
#define SD 64
#define QSCALE 0.18033688011112042f  /* 0.125 * log2(e): Q pre-scale for exp2 softmax */
#define DMTHR 11.541560327111708f    /* defer-max threshold: 8 * log2(e) */

// ---- f32 -> bf16 convert ---------------------------------------------------
__global__ void cvt_f32_bf16(const float* __restrict__ in, unsigned short* __restrict__ out, int n4) {
  int i = blockIdx.x * blockDim.x + threadIdx.x;
  if (i >= n4) return;
  float4 v = ((const float4*)in)[i];
  ushortx4 o;
  o.x = f2bf(v.x); o.y = f2bf(v.y); o.z = f2bf(v.z); o.w = f2bf(v.w);
  ((ushortx4*)out)[i] = o;
}

// ---- NT GEMM: C[m,n] = sum_k A[m,k]*Bw[n,k], both bf16 K-contiguous --------
// 128x128 tile, BK=64, 4 waves (2x2), each wave 64x64 (4x4 MFMA frags).
// Bijective XCD swizzle (m204, nwg%8==0) for L2 locality.
// EPI==0: plain f32 store to Cf[M,N].
// EPI==1: scatter qkv -> Q[B,H,T,D] (pre-scaled by QSCALE), K[B,H,T,D],
//         VT[B,H,D,T] in bf16.
template<int EPI>
__global__ __launch_bounds__(256, 2) void gemm_nt(
    const unsigned short* __restrict__ A, const unsigned short* __restrict__ Bw,
    float* __restrict__ Cf,
    unsigned short* __restrict__ Qo, unsigned short* __restrict__ Ko,
    unsigned short* __restrict__ VTo,
    int M, int N, int K) {
  __shared__ unsigned short As[128 * 64];
  __shared__ unsigned short Bs[128 * 64];
  const int tid = threadIdx.x;
  const int lane = tid & 63;
  const int w = tid >> 6;
  const int wr = w >> 1, wc = w & 1;
  const int r16 = lane & 15, g = lane >> 4;

  // XCD-aware remap: contiguous chunk of blocks per XCD (nwg % 8 == 0)
  const int nwg = gridDim.x * gridDim.y;
  const int lin = blockIdx.x + blockIdx.y * gridDim.x;
  const int wg = (lin & 7) * (nwg >> 3) + (lin >> 3);
  const int bx = wg % gridDim.x, by = wg / gridDim.x;
  const int m0 = by * 128, n0 = bx * 128;

  f32x4 acc[4][4] = {};

  for (int k0 = 0; k0 < K; k0 += 64) {
    __syncthreads();
#pragma unroll
    for (int it = 0; it < 4; ++it) {  // stage A tile [128][64]
      int c = it * 256 + tid;
      int row = c >> 3, cb = (c & 7) * 8;
      gll16(A + (size_t)(m0 + row) * K + k0 + cb, As + c * 8);
    }
#pragma unroll
    for (int it = 0; it < 4; ++it) {  // stage B tile [128][64]
      int c = it * 256 + tid;
      int row = c >> 3, cb = (c & 7) * 8;
      gll16(Bw + (size_t)(n0 + row) * K + k0 + cb, Bs + c * 8);
    }
    __syncthreads();
#pragma unroll
    for (int ks = 0; ks < 2; ++ks) {
      bf16x8 af[4], bfr[4];
#pragma unroll
      for (int mt = 0; mt < 4; ++mt)
        af[mt] = ld8(&As[(wr * 64 + mt * 16 + r16) * 64 + ks * 32 + g * 8]);
#pragma unroll
      for (int nt = 0; nt < 4; ++nt)
        bfr[nt] = ld8(&Bs[(wc * 64 + nt * 16 + r16) * 64 + ks * 32 + g * 8]);
#pragma unroll
      for (int mt = 0; mt < 4; ++mt)
#pragma unroll
        for (int nt = 0; nt < 4; ++nt)
          acc[mt][nt] = MFMA16(af[mt], bfr[nt], acc[mt][nt]);
    }
  }

  // epilogue: C frag layout col = lane&15, row = (lane>>4)*4 + r
#pragma unroll
  for (int mt = 0; mt < 4; ++mt) {
#pragma unroll
    for (int nt = 0; nt < 4; ++nt) {
#pragma unroll
      for (int r = 0; r < 4; ++r) {
        int m = m0 + wr * 64 + mt * 16 + g * 4 + r;
        int n = n0 + wc * 64 + nt * 16 + r16;
        float v = acc[mt][nt][r];
        if (EPI == 0) {
          Cf[(size_t)m * N + n] = v;
        } else {
          int b = m >> 11, t = m & (ST - 1);
          int which = n >> 10, h = (n >> 6) & (SH - 1), d = n & (SD - 1);
          int bh = b * SH + h;
          if (which == 0)
            Qo[((size_t)bh * ST + t) * SD + d] = f2bf(v * QSCALE);
          else if (which == 1)
            Ko[((size_t)bh * ST + t) * SD + d] = f2bf(v);
          else
            VTo[((size_t)bh * SD + d) * ST + t] = f2bf(v);
        }
      }
    }
  }
}

// ---- causal flash attention v5 ---------------------------------------------
// QBLK=128 (4 waves x 32 q-cols), KVBLK=64, double-buffered K/V, XOR swizzle.
// 32x32x16 MFMA, swapped operands (S^T = mfma(K,Q)); softmax in-register with
// permlane32_swap P-redistribution (T12). exp2-domain with the QK accumulator
// SEEDED at -mrow -> no subtract in the common defer-max path (T13). Row sums
// via MFMA ones-trick into a persistent ls_acc. XCD-affinity block swizzle:
// each head's 16 q-blocks pinned to one XCD, globally heavy-first.

DEVI void stage_tile(const unsigned short* gbase, size_t rowstride,
                     unsigned short* lds, int tid) {
#pragma unroll
  for (int it = 0; it < 2; ++it) {
    int c = it * 256 + tid;
    int row = c >> 3, j = c & 7;
    int src = ((j * 16) ^ ((row & 7) << 4)) >> 1;  // shorts
    gll16(gbase + (size_t)row * rowstride + src, lds + c * 8);
  }
}

DEVI bf16x8 ldswz(const unsigned short* L, int row, int colsh) {  // swizzled read
  return ld8(L + row * 64 + ((((colsh * 2) ^ ((row & 7) << 4))) >> 1));
}

__global__ __launch_bounds__(256, 4) void attn_causal(
    const unsigned short* __restrict__ Q, const unsigned short* __restrict__ Kv,
    const unsigned short* __restrict__ VT, unsigned short* __restrict__ Y) {
  __shared__ unsigned short Ks[2][64 * 64];   // [t][d], swizzled
  __shared__ unsigned short Vs[2][64 * 64];   // [d][t], swizzled

  const int tid = threadIdx.x;
  const int lane = tid & 63;
  const int w = tid >> 6;
  const int l5 = lane & 31, h = lane >> 5;

  // XCD-affinity remap: xcd = lin&7 handles heads {xcd, xcd+8, ...};
  // qt descending with idx -> all 64 heads' heaviest blocks dispatch first.
  const int lin = blockIdx.x + blockIdx.y * gridDim.x;  // 0..1023
  const int xcd = lin & 7;
  const int idx = lin >> 3;                 // 0..127
  const int qt = (ST / 128 - 1) - (idx >> 3);
  const int bh = xcd + 8 * (idx & 7);
  const size_t base = (size_t)bh * ST * SD;

  const int q_glob = qt * 128 + w * 32 + l5;   // this lane's q-row
  const int qwmin = qt * 128 + w * 32;         // wave q range [qwmin, qwmin+31]

  // Q B-fragments: col n = q = lane&31, k = h*8 + i, chained over kk (d-slices)
  bf16x8 qf[4];
#pragma unroll
  for (int kk = 0; kk < 4; ++kk)
    qf[kk] = ld8(Q + base + (size_t)q_glob * SD + kk * 16 + h * 8);

  bf16x8 onesf;
#pragma unroll
  for (int i = 0; i < 8; ++i) onesf[i] = (__bf16)1.0f;

  float mrow = 0.f;       // running max (log2 domain); 0-init safe, scale cancels
  f32x16 ls_acc = {};     // row-sum accumulator via ones-MFMA; lrow = ls_acc[0]
  f32x16 acc[2] = {};     // O^T: lane q=l5, d = dblk*32 + (reg&3) + 4h + 8*(reg>>2)

  const int nkv = 2 * qt + 2;
  stage_tile(Kv + base, SD, Ks[0], tid);
  stage_tile(VT + base, ST, Vs[0], tid);
  __syncthreads();

  for (int kvt = 0; kvt < nkv; ++kvt) {
    const int cur = kvt & 1;
    if (kvt + 1 < nkv) {  // prefetch next tile into other buffer
      stage_tile(Kv + base + (size_t)(kvt + 1) * 64 * SD, SD, Ks[cur ^ 1], tid);
      stage_tile(VT + base + (kvt + 1) * 64, ST, Vs[cur ^ 1], tid);
    }

    // tiles fully above this wave's q range contribute nothing
    const bool active = (kvt * 64) <= (qwmin + 31);
    if (active) {
      // S' = K Q^T - mrow (accumulator seeded at -mrow); lane owns q=l5
      f32x16 s0, s1;
      const float negm = -mrow;
#pragma unroll
      for (int i = 0; i < 16; ++i) { s0[i] = negm; s1[i] = negm; }
      __builtin_amdgcn_s_setprio(1);
#pragma unroll
      for (int kk = 0; kk < 4; ++kk) {
        bf16x8 k0 = ldswz(Ks[cur], l5, kk * 16 + h * 8);
        s0 = MFMA32(k0, qf[kk], s0);
      }
#pragma unroll
      for (int kk = 0; kk < 4; ++kk) {
        bf16x8 k1 = ldswz(Ks[cur], 32 + l5, kk * 16 + h * 8);
        s1 = MFMA32(k1, qf[kk], s1);
      }
      __builtin_amdgcn_s_setprio(0);

      if (kvt * 64 + 63 > qwmin) {  // diagonal overlap: causal mask
        const int t0 = kvt * 64 + 4 * h;
#pragma unroll
        for (int reg = 0; reg < 16; ++reg) {
          int t = t0 + (reg & 3) + 8 * (reg >> 2);
          if (t > q_glob) s0[reg] = -__builtin_inff();
          if (t + 32 > q_glob) s1[reg] = -__builtin_inff();
        }
      }

      // row max (relative to mrow): in-lane tree + one half-swap
      f32x16 mx;
#pragma unroll
      for (int i = 0; i < 16; ++i) mx[i] = fmaxf(s0[i], s1[i]);
#pragma unroll
      for (int i = 0; i < 8; ++i) mx[i] = fmaxf(mx[i], mx[i + 8]);
#pragma unroll
      for (int i = 0; i < 4; ++i) mx[i] = fmaxf(mx[i], mx[i + 4]);
      float bm = fmaxf(fmaxf(mx[0], mx[1]), fmaxf(mx[2], mx[3]));
      bm = swaphalf_max(bm);

      if (__any(bm > DMTHR)) {  // rare: rescale path
        float delta = fmaxf(bm, 0.f);
        float corr = exp2f(-delta);
        mrow += delta;
#pragma unroll
        for (int dblk = 0; dblk < 2; ++dblk)
#pragma unroll
          for (int i = 0; i < 16; ++i) acc[dblk][i] *= corr;
#pragma unroll
        for (int i = 0; i < 16; ++i) ls_acc[i] *= corr;
#pragma unroll
        for (int i = 0; i < 16; ++i) {
          s0[i] = exp2f(s0[i] - delta);
          s1[i] = exp2f(s1[i] - delta);
        }
      } else {  // common: no subtract at all
#pragma unroll
        for (int i = 0; i < 16; ++i) {
          s0[i] = exp2f(s0[i]);
          s1[i] = exp2f(s1[i]);
        }
      }

      // pack P -> bf16 PV B-fragments via permlane32_swap (no LDS roundtrip)
      bf16x8 pb[2][2];
      auto packblk = [&](const f32x16& S, bf16x8* out) {
        unsigned a = pkbf(S[0], S[1]), b2 = pkbf(S[2], S[3]);
        unsigned c = pkbf(S[4], S[5]), d2 = pkbf(S[6], S[7]);
        auto r0 = __builtin_amdgcn_permlane32_swap(a, c, false, false);
        auto r1 = __builtin_amdgcn_permlane32_swap(b2, d2, false, false);
        uint32x4v w0 = {(unsigned)r0[0], (unsigned)r1[0], (unsigned)r0[1], (unsigned)r1[1]};
        out[0] = __builtin_bit_cast(bf16x8, w0);
        unsigned e = pkbf(S[8], S[9]), f2 = pkbf(S[10], S[11]);
        unsigned g2 = pkbf(S[12], S[13]), h2 = pkbf(S[14], S[15]);
        auto r2 = __builtin_amdgcn_permlane32_swap(e, g2, false, false);
        auto r3 = __builtin_amdgcn_permlane32_swap(f2, h2, false, false);
        uint32x4v w1 = {(unsigned)r2[0], (unsigned)r3[0], (unsigned)r2[1], (unsigned)r3[1]};
        out[1] = __builtin_bit_cast(bf16x8, w1);
      };
      packblk(s0, pb[0]);
      packblk(s1, pb[1]);

      __builtin_amdgcn_s_setprio(1);
      // row sums via ones-MFMA: every reg of ls_acc accumulates sum_t P[t][q]
#pragma unroll
      for (int tt = 0; tt < 2; ++tt)
#pragma unroll
        for (int sl = 0; sl < 2; ++sl)
          ls_acc = MFMA32(onesf, pb[tt][sl], ls_acc);

      // O^T += V^T P^T : A = V^T (d rows), B = P^T (q cols)
#pragma unroll
      for (int dblk = 0; dblk < 2; ++dblk)
#pragma unroll
        for (int tt = 0; tt < 2; ++tt)
#pragma unroll
          for (int sl = 0; sl < 2; ++sl) {
            bf16x8 va = ldswz(Vs[cur], dblk * 32 + l5, tt * 32 + sl * 16 + h * 8);
            acc[dblk] = MFMA32(va, pb[tt][sl], acc[dblk]);
          }
      __builtin_amdgcn_s_setprio(0);
    }

    __syncthreads();  // drains vmcnt (next tile staged) + guards buffer reuse
  }

  // epilogue: Y[B,T,E] bf16, e = head*64 + d; 4 consecutive d per reg-group
  const int b = bh >> 4, hd = bh & 15;
  const float inv = 1.f / ls_acc[0];
#pragma unroll
  for (int dblk = 0; dblk < 2; ++dblk)
#pragma unroll
    for (int rg = 0; rg < 4; ++rg) {
      bf16x4 o;
#pragma unroll
      for (int j = 0; j < 4; ++j) o[j] = (__bf16)(acc[dblk][rg * 4 + j] * inv);
      int d = dblk * 32 + rg * 8 + 4 * h;
      *(ushortx4*)&Y[((size_t)b * ST + q_glob) * SE + hd * SD + d] =
          __builtin_bit_cast(ushortx4, o);
    }
}

// ---- launch ----------------------------------------------------------------
extern "C" void kernel_launch(void* const* d_in, const int* in_sizes, int n_in,
                              void* d_out, int out_size, void* d_ws, size_t ws_size,
                              hipStream_t stream) {
  const float* x = (const float*)d_in[0];       // [4,2048,1024]
  const float* w_qkv = (const float*)d_in[1];   // [3072,1024]
  const float* w_out = (const float*)d_in[2];   // [1024,1024]
  float* out = (float*)d_out;                   // [4,2048,1024] f32

  const size_t NX = (size_t)SB * ST * SE;       // 8388608
  const size_t NQKV = (size_t)3 * SE * SE;      // 3145728
  const size_t NWO = (size_t)SE * SE;           // 1048576
  const size_t NHD = (size_t)SB * SH * ST * SD; // 8388608

  unsigned short* xb    = (unsigned short*)d_ws;        // 16MB, reused as Y later
  unsigned short* wqkvb = xb + NX;                      // 6MB
  unsigned short* woutb = wqkvb + NQKV;                 // 2MB
  unsigned short* q     = woutb + NWO;                  // 16MB
  unsigned short* k     = q + NHD;                      // 16MB
  unsigned short* vT    = k + NHD;                      // 16MB
  unsigned short* y     = xb;                           // alias (xb dead after GEMM1)

  cvt_f32_bf16<<<(int)(NX / 4 + 255) / 256, 256, 0, stream>>>(x, xb, (int)(NX / 4));
  cvt_f32_bf16<<<(int)(NQKV / 4 + 255) / 256, 256, 0, stream>>>(w_qkv, wqkvb, (int)(NQKV / 4));
  cvt_f32_bf16<<<(int)(NWO / 4 + 255) / 256, 256, 0, stream>>>(w_out, woutb, (int)(NWO / 4));

  // qkv = x @ w_qkv^T, scattered into Q/K/VT
  gemm_nt<1><<<dim3(3 * SE / 128, SB * ST / 128), 256, 0, stream>>>(
      xb, wqkvb, nullptr, q, k, vT, SB * ST, 3 * SE, SE);

  attn_causal<<<dim3(ST / 128, SB * SH), 256, 0, stream>>>(q, k, vT, y);

  // out = y @ w_out^T (f32 out)
  gemm_nt<0><<<dim3(SE / 128, SB * ST / 128), 256, 0, stream>>>(
      y, woutb, out, nullptr, nullptr, nullptr, SB * ST, SE, SE);
}

// Round 6
// 203.643 us; speedup vs baseline: 2.4611x; 2.4611x over previous
//
#include <hip/hip_runtime.h>

// ---- types / helpers -------------------------------------------------------
typedef __bf16 bf16x8 __attribute__((ext_vector_type(8)));
typedef __bf16 bf16x4 __attribute__((ext_vector_type(4)));
typedef __bf16 bf16x2 __attribute__((ext_vector_type(2)));
typedef float f32x4 __attribute__((ext_vector_type(4)));
typedef float f32x16 __attribute__((ext_vector_type(16)));
typedef unsigned short ushortx8 __attribute__((ext_vector_type(8)));
typedef unsigned short ushortx4 __attribute__((ext_vector_type(4)));
typedef unsigned int uint32x4v __attribute__((ext_vector_type(4)));

#define DEVI static __device__ __forceinline__

DEVI unsigned short f2bf(float f) {  // round-to-nearest-even f32 -> bf16
  unsigned int u = __builtin_bit_cast(unsigned int, f);
  u += 0x7FFFu + ((u >> 16) & 1u);
  return (unsigned short)(u >> 16);
}

DEVI bf16x8 ld8(const unsigned short* p) {  // 16B vector load (global or LDS)
  return __builtin_bit_cast(bf16x8, *(const ushortx8*)p);
}

DEVI void gll16(const unsigned short* g, unsigned short* l) {  // global->LDS 16B DMA
  __builtin_amdgcn_global_load_lds((const __attribute__((address_space(1))) void*)g,
                                   (__attribute__((address_space(3))) void*)l, 16, 0, 0);
}

#define MFMA16(a, b, c) __builtin_amdgcn_mfma_f32_16x16x32_bf16(a, b, c, 0, 0, 0)
#define MFMA32(a, b, c) __builtin_amdgcn_mfma_f32_32x32x16_bf16(a, b, c, 0, 0, 0)

DEVI unsigned pkbf(float lo, float hi) {  // pack 2 f32 -> u32 of 2 bf16 (lo in low16)
  bf16x2 v;
  v[0] = (__bf16)lo;
  v[1] = (__bf16)hi;
  return __builtin_bit_cast(unsigned, v);
}

DEVI float swaphalf_max(float x) {  // max(own, other-32-lane-half) for all lanes
  unsigned xu = __builtin_bit_cast(unsigned, x);
  auto pr = __builtin_amdgcn_permlane32_swap(xu, xu, false, false);
  return fmaxf(__builtin_bit_cast(float, (unsigned)pr[0]),
               __builtin_bit_cast(float, (unsigned)pr[1]));
}

DEVI float swaphalf_add(float x) {
  unsigned xu = __builtin_bit_cast(unsigned, x);
  auto pr = __builtin_amdgcn_permlane32_swap(xu, xu, false, false);
  return __builtin_bit_cast(float, (unsigned)pr[0]) +
         __builtin_bit_cast(float, (unsigned)pr[1]);
}

// ---- problem constants -----------------------------------------------------
// B=4, T=2048, E=1024, H=16, D=64
#define SB 4
#define ST 2048
#define SE 1024
#define SH 16
#define SD 64
#define QSCALE 0.18033688011112042f  /* 0.125 * log2(e): Q pre-scale for exp2 softmax */
#define DMTHR 11.541560327111708f    /* defer-max threshold: 8 * log2(e) */

// ---- f32 -> bf16 convert ---------------------------------------------------
__global__ void cvt_f32_bf16(const float* __restrict__ in, unsigned short* __restrict__ out, int n4) {
  int i = blockIdx.x * blockDim.x + threadIdx.x;
  if (i >= n4) return;
  float4 v = ((const float4*)in)[i];
  ushortx4 o;
  o.x = f2bf(v.x); o.y = f2bf(v.y); o.z = f2bf(v.z); o.w = f2bf(v.w);
  ((ushortx4*)out)[i] = o;
}

// ---- NT GEMM: C[m,n] = sum_k A[m,k]*Bw[n,k], both bf16 K-contiguous --------
// 128x128 tile, BK=64, 4 waves (2x2), each wave 64x64 (4x4 MFMA frags).
// Bijective XCD swizzle (nwg%8==0) for L2 locality.
// EPI==0: plain f32 store to Cf[M,N].
// EPI==1: scatter qkv -> Q[B,H,T,D] (pre-scaled by QSCALE), K[B,H,T,D],
//         VT[B,H,D,T] in bf16.
template<int EPI>
__global__ __launch_bounds__(256, 2) void gemm_nt(
    const unsigned short* __restrict__ A, const unsigned short* __restrict__ Bw,
    float* __restrict__ Cf,
    unsigned short* __restrict__ Qo, unsigned short* __restrict__ Ko,
    unsigned short* __restrict__ VTo,
    int M, int N, int K) {
  __shared__ unsigned short As[128 * 64];
  __shared__ unsigned short Bs[128 * 64];
  const int tid = threadIdx.x;
  const int lane = tid & 63;
  const int w = tid >> 6;
  const int wr = w >> 1, wc = w & 1;
  const int r16 = lane & 15, g = lane >> 4;

  // XCD-aware remap: contiguous chunk of blocks per XCD (nwg % 8 == 0)
  const int nwg = gridDim.x * gridDim.y;
  const int lin = blockIdx.x + blockIdx.y * gridDim.x;
  const int wg = (lin & 7) * (nwg >> 3) + (lin >> 3);
  const int bx = wg % gridDim.x, by = wg / gridDim.x;
  const int m0 = by * 128, n0 = bx * 128;

  f32x4 acc[4][4] = {};

  for (int k0 = 0; k0 < K; k0 += 64) {
    __syncthreads();
#pragma unroll
    for (int it = 0; it < 4; ++it) {  // stage A tile [128][64]
      int c = it * 256 + tid;
      int row = c >> 3, cb = (c & 7) * 8;
      gll16(A + (size_t)(m0 + row) * K + k0 + cb, As + c * 8);
    }
#pragma unroll
    for (int it = 0; it < 4; ++it) {  // stage B tile [128][64]
      int c = it * 256 + tid;
      int row = c >> 3, cb = (c & 7) * 8;
      gll16(Bw + (size_t)(n0 + row) * K + k0 + cb, Bs + c * 8);
    }
    __syncthreads();
#pragma unroll
    for (int ks = 0; ks < 2; ++ks) {
      bf16x8 af[4], bfr[4];
#pragma unroll
      for (int mt = 0; mt < 4; ++mt)
        af[mt] = ld8(&As[(wr * 64 + mt * 16 + r16) * 64 + ks * 32 + g * 8]);
#pragma unroll
      for (int nt = 0; nt < 4; ++nt)
        bfr[nt] = ld8(&Bs[(wc * 64 + nt * 16 + r16) * 64 + ks * 32 + g * 8]);
#pragma unroll
      for (int mt = 0; mt < 4; ++mt)
#pragma unroll
        for (int nt = 0; nt < 4; ++nt)
          acc[mt][nt] = MFMA16(af[mt], bfr[nt], acc[mt][nt]);
    }
  }

  // epilogue: C frag layout col = lane&15, row = (lane>>4)*4 + r
#pragma unroll
  for (int mt = 0; mt < 4; ++mt) {
#pragma unroll
    for (int nt = 0; nt < 4; ++nt) {
#pragma unroll
      for (int r = 0; r < 4; ++r) {
        int m = m0 + wr * 64 + mt * 16 + g * 4 + r;
        int n = n0 + wc * 64 + nt * 16 + r16;
        float v = acc[mt][nt][r];
        if (EPI == 0) {
          Cf[(size_t)m * N + n] = v;
        } else {
          int b = m >> 11, t = m & (ST - 1);
          int which = n >> 10, h = (n >> 6) & (SH - 1), d = n & (SD - 1);
          int bh = b * SH + h;
          if (which == 0)
            Qo[((size_t)bh * ST + t) * SD + d] = f2bf(v * QSCALE);
          else if (which == 1)
            Ko[((size_t)bh * ST + t) * SD + d] = f2bf(v);
          else
            VTo[((size_t)bh * SD + d) * ST + t] = f2bf(v);
        }
      }
    }
  }
}

// ---- causal flash attention v6 (= v4 body + XCD-affinity remap) ------------
// QBLK=128 (4 waves x 32 q-cols), KVBLK=64, double-buffered K/V, XOR swizzle.
// 32x32x16 MFMA, swapped operands: S^T = mfma(K, Q). Softmax fully in-register;
// P redistributed to PV B-fragments via permlane32_swap (T12). exp2-domain,
// defer-max (T13). XCD-affinity: each XCD's co-resident blocks cover 8 heads
// (KV working set 4 MB = one L2), globally heavy-first.
// NOTE (R5 post-mortem): do NOT add accumulator state here — at
// __launch_bounds__(256,4) the VGPR budget is 128/wave and R4's body sits
// just under it; +20 VGPRs (ls_acc trick) caused 975 MB of scratch spill.

DEVI void stage_tile(const unsigned short* gbase, size_t rowstride,
                     unsigned short* lds, int tid) {
#pragma unroll
  for (int it = 0; it < 2; ++it) {
    int c = it * 256 + tid;
    int row = c >> 3, j = c & 7;
    int src = ((j * 16) ^ ((row & 7) << 4)) >> 1;  // shorts
    gll16(gbase + (size_t)row * rowstride + src, lds + c * 8);
  }
}

DEVI bf16x8 ldswz(const unsigned short* L, int row, int colsh) {  // swizzled read
  return ld8(L + row * 64 + ((((colsh * 2) ^ ((row & 7) << 4))) >> 1));
}

__global__ __launch_bounds__(256, 4) void attn_causal(
    const unsigned short* __restrict__ Q, const unsigned short* __restrict__ Kv,
    const unsigned short* __restrict__ VT, unsigned short* __restrict__ Y) {
  __shared__ unsigned short Ks[2][64 * 64];   // [t][d], swizzled
  __shared__ unsigned short Vs[2][64 * 64];   // [d][t], swizzled

  const int tid = threadIdx.x;
  const int lane = tid & 63;
  const int w = tid >> 6;
  const int l5 = lane & 31, h = lane >> 5;

  // XCD-affinity remap: xcd = lin&7 handles heads {xcd, xcd+8, ...};
  // qt descending -> all 64 heads' heaviest blocks dispatch first.
  const int lin = blockIdx.x + blockIdx.y * gridDim.x;  // 0..1023
  const int xcd = lin & 7;
  const int idx = lin >> 3;                 // 0..127
  const int qt = (ST / 128 - 1) - (idx >> 3);
  const int bh = xcd + 8 * (idx & 7);
  const size_t base = (size_t)bh * ST * SD;

  const int q_glob = qt * 128 + w * 32 + l5;   // this lane's q-row
  const int qwmin = qt * 128 + w * 32;         // wave q range [qwmin, qwmin+31]

  // Q B-fragments: col n = q = lane&31, k = h*8 + i, chained over kk (d-slices)
  bf16x8 qf[4];
#pragma unroll
  for (int kk = 0; kk < 4; ++kk)
    qf[kk] = ld8(Q + base + (size_t)q_glob * SD + kk * 16 + h * 8);

  float mrow = -__builtin_inff();
  float lrow = 0.f;
  f32x16 acc[2] = {};  // O^T: lane q=l5, d = dblk*32 + (reg&3) + 4h + 8*(reg>>2)

  const int nkv = 2 * qt + 2;
  stage_tile(Kv + base, SD, Ks[0], tid);
  stage_tile(VT + base, ST, Vs[0], tid);
  __syncthreads();

  for (int kvt = 0; kvt < nkv; ++kvt) {
    const int cur = kvt & 1;
    if (kvt + 1 < nkv) {  // prefetch next tile into other buffer
      stage_tile(Kv + base + (size_t)(kvt + 1) * 64 * SD, SD, Ks[cur ^ 1], tid);
      stage_tile(VT + base + (kvt + 1) * 64, ST, Vs[cur ^ 1], tid);
    }

    // tiles fully above this wave's q range contribute nothing
    const bool active = (kvt * 64) <= (qwmin + 31);
    if (active) {
      // S^T = K Q^T : two 32t x 32q blocks; lane owns q=l5, t-half per h
      f32x16 s0 = {}, s1 = {};
      __builtin_amdgcn_s_setprio(1);
#pragma unroll
      for (int kk = 0; kk < 4; ++kk) {
        bf16x8 k0 = ldswz(Ks[cur], l5, kk * 16 + h * 8);
        s0 = MFMA32(k0, qf[kk], s0);
      }
#pragma unroll
      for (int kk = 0; kk < 4; ++kk) {
        bf16x8 k1 = ldswz(Ks[cur], 32 + l5, kk * 16 + h * 8);
        s1 = MFMA32(k1, qf[kk], s1);
      }
      __builtin_amdgcn_s_setprio(0);

      if (kvt * 64 + 63 > qwmin) {  // diagonal overlap: causal mask
        const int t0 = kvt * 64 + 4 * h;
#pragma unroll
        for (int reg = 0; reg < 16; ++reg) {
          int t = t0 + (reg & 3) + 8 * (reg >> 2);
          if (t > q_glob) s0[reg] = -__builtin_inff();
          if (t + 32 > q_glob) s1[reg] = -__builtin_inff();
        }
      }

      // row max: elementwise + in-lane tree + one half-swap
      f32x16 mx;
#pragma unroll
      for (int i = 0; i < 16; ++i) mx[i] = fmaxf(s0[i], s1[i]);
#pragma unroll
      for (int i = 0; i < 8; ++i) mx[i] = fmaxf(mx[i], mx[i + 8]);
#pragma unroll
      for (int i = 0; i < 4; ++i) mx[i] = fmaxf(mx[i], mx[i + 4]);
      float bm = fmaxf(fmaxf(mx[0], mx[1]), fmaxf(mx[2], mx[3]));
      bm = swaphalf_max(bm);

      // defer-max: rescale only if running max grew by more than DMTHR
      if (__any(bm > mrow + DMTHR)) {
        float mn = fmaxf(mrow, bm);
        float corr = exp2f(mrow - mn);  // first tile: exp2(-inf)=0
        mrow = mn;
        lrow *= corr;
#pragma unroll
        for (int dblk = 0; dblk < 2; ++dblk)
#pragma unroll
          for (int i = 0; i < 16; ++i) acc[dblk][i] *= corr;
      }

      // P = exp2(S - m), in-lane sum + half-swap
#pragma unroll
      for (int i = 0; i < 16; ++i) {
        s0[i] = exp2f(s0[i] - mrow);
        s1[i] = exp2f(s1[i] - mrow);
      }
      f32x16 sm;
#pragma unroll
      for (int i = 0; i < 16; ++i) sm[i] = s0[i] + s1[i];
#pragma unroll
      for (int i = 0; i < 8; ++i) sm[i] += sm[i + 8];
#pragma unroll
      for (int i = 0; i < 4; ++i) sm[i] += sm[i + 4];
      float rs = (sm[0] + sm[1]) + (sm[2] + sm[3]);
      lrow += swaphalf_add(rs);

      // pack P -> bf16 PV B-fragments via permlane32_swap (no LDS roundtrip)
      bf16x8 pb[2][2];
      auto packblk = [&](const f32x16& S, bf16x8* out) {
        unsigned a = pkbf(S[0], S[1]), b2 = pkbf(S[2], S[3]);
        unsigned c = pkbf(S[4], S[5]), d2 = pkbf(S[6], S[7]);
        auto r0 = __builtin_amdgcn_permlane32_swap(a, c, false, false);
        auto r1 = __builtin_amdgcn_permlane32_swap(b2, d2, false, false);
        uint32x4v w0 = {(unsigned)r0[0], (unsigned)r1[0], (unsigned)r0[1], (unsigned)r1[1]};
        out[0] = __builtin_bit_cast(bf16x8, w0);
        unsigned e = pkbf(S[8], S[9]), f2 = pkbf(S[10], S[11]);
        unsigned g2 = pkbf(S[12], S[13]), h2 = pkbf(S[14], S[15]);
        auto r2 = __builtin_amdgcn_permlane32_swap(e, g2, false, false);
        auto r3 = __builtin_amdgcn_permlane32_swap(f2, h2, false, false);
        uint32x4v w1 = {(unsigned)r2[0], (unsigned)r3[0], (unsigned)r2[1], (unsigned)r3[1]};
        out[1] = __builtin_bit_cast(bf16x8, w1);
      };
      packblk(s0, pb[0]);
      packblk(s1, pb[1]);

      // O^T += V^T P^T : A = V^T (d rows), B = P^T (q cols)
      __builtin_amdgcn_s_setprio(1);
#pragma unroll
      for (int dblk = 0; dblk < 2; ++dblk)
#pragma unroll
        for (int tt = 0; tt < 2; ++tt)
#pragma unroll
          for (int sl = 0; sl < 2; ++sl) {
            bf16x8 va = ldswz(Vs[cur], dblk * 32 + l5, tt * 32 + sl * 16 + h * 8);
            acc[dblk] = MFMA32(va, pb[tt][sl], acc[dblk]);
          }
      __builtin_amdgcn_s_setprio(0);
    }

    __syncthreads();  // drains vmcnt (next tile staged) + guards buffer reuse
  }

  // epilogue: Y[B,T,E] bf16, e = head*64 + d; 4 consecutive d per reg-group
  const int b = bh >> 4, hd = bh & 15;
  const float inv = 1.f / lrow;
#pragma unroll
  for (int dblk = 0; dblk < 2; ++dblk)
#pragma unroll
    for (int rg = 0; rg < 4; ++rg) {
      bf16x4 o;
#pragma unroll
      for (int j = 0; j < 4; ++j) o[j] = (__bf16)(acc[dblk][rg * 4 + j] * inv);
      int d = dblk * 32 + rg * 8 + 4 * h;
      *(ushortx4*)&Y[((size_t)b * ST + q_glob) * SE + hd * SD + d] =
          __builtin_bit_cast(ushortx4, o);
    }
}

// ---- launch ----------------------------------------------------------------
extern "C" void kernel_launch(void* const* d_in, const int* in_sizes, int n_in,
                              void* d_out, int out_size, void* d_ws, size_t ws_size,
                              hipStream_t stream) {
  const float* x = (const float*)d_in[0];       // [4,2048,1024]
  const float* w_qkv = (const float*)d_in[1];   // [3072,1024]
  const float* w_out = (const float*)d_in[2];   // [1024,1024]
  float* out = (float*)d_out;                   // [4,2048,1024] f32

  const size_t NX = (size_t)SB * ST * SE;       // 8388608
  const size_t NQKV = (size_t)3 * SE * SE;      // 3145728
  const size_t NWO = (size_t)SE * SE;           // 1048576
  const size_t NHD = (size_t)SB * SH * ST * SD; // 8388608

  unsigned short* xb    = (unsigned short*)d_ws;        // 16MB, reused as Y later
  unsigned short* wqkvb = xb + NX;                      // 6MB
  unsigned short* woutb = wqkvb + NQKV;                 // 2MB
  unsigned short* q     = woutb + NWO;                  // 16MB
  unsigned short* k     = q + NHD;                      // 16MB
  unsigned short* vT    = k + NHD;                      // 16MB
  unsigned short* y     = xb;                           // alias (xb dead after GEMM1)

  cvt_f32_bf16<<<(int)(NX / 4 + 255) / 256, 256, 0, stream>>>(x, xb, (int)(NX / 4));
  cvt_f32_bf16<<<(int)(NQKV / 4 + 255) / 256, 256, 0, stream>>>(w_qkv, wqkvb, (int)(NQKV / 4));
  cvt_f32_bf16<<<(int)(NWO / 4 + 255) / 256, 256, 0, stream>>>(w_out, woutb, (int)(NWO / 4));

  // qkv = x @ w_qkv^T, scattered into Q/K/VT
  gemm_nt<1><<<dim3(3 * SE / 128, SB * ST / 128), 256, 0, stream>>>(
      xb, wqkvb, nullptr, q, k, vT, SB * ST, 3 * SE, SE);

  attn_causal<<<dim3(ST / 128, SB * SH), 256, 0, stream>>>(q, k, vT, y);

  // out = y @ w_out^T (f32 out)
  gemm_nt<0><<<dim3(SE / 128, SB * ST / 128), 256, 0, stream>>>(
      y, woutb, out, nullptr, nullptr, nullptr, SB * ST, SE, SE);
}

// Round 7
// 199.203 us; speedup vs baseline: 2.5159x; 1.0223x over previous
//
#include <hip/hip_runtime.h>

// ---- types / helpers -------------------------------------------------------
typedef __bf16 bf16x8 __attribute__((ext_vector_type(8)));
typedef __bf16 bf16x4 __attribute__((ext_vector_type(4)));
typedef __bf16 bf16x2 __attribute__((ext_vector_type(2)));
typedef float f32x4 __attribute__((ext_vector_type(4)));
typedef float f32x16 __attribute__((ext_vector_type(16)));
typedef unsigned short ushortx8 __attribute__((ext_vector_type(8)));
typedef unsigned short ushortx4 __attribute__((ext_vector_type(4)));
typedef unsigned int uint32x4v __attribute__((ext_vector_type(4)));

#define DEVI static __device__ __forceinline__

DEVI unsigned short f2bf(float f) {  // round-to-nearest-even f32 -> bf16
  unsigned int u = __builtin_bit_cast(unsigned int, f);
  u += 0x7FFFu + ((u >> 16) & 1u);
  return (unsigned short)(u >> 16);
}

DEVI bf16x8 ld8(const unsigned short* p) {  // 16B vector load (global or LDS)
  return __builtin_bit_cast(bf16x8, *(const ushortx8*)p);
}

DEVI void gll16(const unsigned short* g, unsigned short* l) {  // global->LDS 16B DMA
  __builtin_amdgcn_global_load_lds((const __attribute__((address_space(1))) void*)g,
                                   (__attribute__((address_space(3))) void*)l, 16, 0, 0);
}

#define MFMA16(a, b, c) __builtin_amdgcn_mfma_f32_16x16x32_bf16(a, b, c, 0, 0, 0)
#define MFMA32(a, b, c) __builtin_amdgcn_mfma_f32_32x32x16_bf16(a, b, c, 0, 0, 0)

DEVI unsigned pkbf(float lo, float hi) {  // pack 2 f32 -> u32 of 2 bf16 (lo in low16)
  bf16x2 v;
  v[0] = (__bf16)lo;
  v[1] = (__bf16)hi;
  return __builtin_bit_cast(unsigned, v);
}

DEVI float swaphalf_max(float x) {  // max(own, other-32-lane-half) for all lanes
  unsigned xu = __builtin_bit_cast(unsigned, x);
  auto pr = __builtin_amdgcn_permlane32_swap(xu, xu, false, false);
  return fmaxf(__builtin_bit_cast(float, (unsigned)pr[0]),
               __builtin_bit_cast(float, (unsigned)pr[1]));
}

DEVI float swaphalf_add(float x) {
  unsigned xu = __builtin_bit_cast(unsigned, x);
  auto pr = __builtin_amdgcn_permlane32_swap(xu, xu, false, false);
  return __builtin_bit_cast(float, (unsigned)pr[0]) +
         __builtin_bit_cast(float, (unsigned)pr[1]);
}

// XOR-swizzled LDS helpers for 64-short (128 B) rows: byte ^= (row&7)<<4,
// applied on BOTH sides (pre-swizzled global source + swizzled ds_read).
DEVI bf16x8 ldswz(const unsigned short* L, int row, int colsh) {  // swizzled read
  return ld8(L + row * 64 + ((((colsh * 2) ^ ((row & 7) << 4))) >> 1));
}

// ---- problem constants -----------------------------------------------------
// B=4, T=2048, E=1024, H=16, D=64
#define SB 4
#define ST 2048
#define SE 1024
#define SH 16
#define SD 64
#define QSCALE 0.18033688011112042f  /* 0.125 * log2(e): Q pre-scale for exp2 softmax */
#define DMTHR 11.541560327111708f    /* defer-max threshold: 8 * log2(e) */

// ---- f32 -> bf16 convert ---------------------------------------------------
__global__ void cvt_f32_bf16(const float* __restrict__ in, unsigned short* __restrict__ out, int n4) {
  int i = blockIdx.x * blockDim.x + threadIdx.x;
  if (i >= n4) return;
  float4 v = ((const float4*)in)[i];
  ushortx4 o;
  o.x = f2bf(v.x); o.y = f2bf(v.y); o.z = f2bf(v.z); o.w = f2bf(v.w);
  ((ushortx4*)out)[i] = o;
}

// ---- NT GEMM v2: C[m,n] = sum_k A[m,k]*Bw[n,k], both bf16 K-contiguous -----
// 128x128 tile, BK=64, 4 waves (2x2), each wave 64x64 (4x4 MFMA frags).
// Double-buffered LDS with stage-ahead order (stage t+1 -> compute t ->
// syncthreads): the vmcnt(0) drain lands AFTER compute, hiding load latency.
// XOR swizzle (row&7)<<4 on both sides kills the 16-lane ds_read conflicts.
// Bijective XCD swizzle (nwg%8==0) for L2 locality.
// EPI==0: plain f32 store to Cf[M,N].
// EPI==1: scatter qkv -> Q[B,H,T,D] (pre-scaled by QSCALE), K[B,H,T,D],
//         VT[B,H,D,T] in bf16.
template<int EPI>
__global__ __launch_bounds__(256, 2) void gemm_nt(
    const unsigned short* __restrict__ A, const unsigned short* __restrict__ Bw,
    float* __restrict__ Cf,
    unsigned short* __restrict__ Qo, unsigned short* __restrict__ Ko,
    unsigned short* __restrict__ VTo,
    int M, int N, int K) {
  __shared__ unsigned short As[2][128 * 64];
  __shared__ unsigned short Bs[2][128 * 64];
  const int tid = threadIdx.x;
  const int lane = tid & 63;
  const int w = tid >> 6;
  const int wr = w >> 1, wc = w & 1;
  const int r16 = lane & 15, g = lane >> 4;

  // XCD-aware remap: contiguous chunk of blocks per XCD (nwg % 8 == 0)
  const int nwg = gridDim.x * gridDim.y;
  const int lin = blockIdx.x + blockIdx.y * gridDim.x;
  const int wg = (lin & 7) * (nwg >> 3) + (lin >> 3);
  const int bx = wg % gridDim.x, by = wg / gridDim.x;
  const int m0 = by * 128, n0 = bx * 128;

  f32x4 acc[4][4] = {};

  // stage one 128x64 A-tile + B-tile pair into buffer `buf`, source
  // pre-swizzled so swizzled ds_reads see the right data (rule 21).
  auto stageAB = [&](int k0, int buf) {
#pragma unroll
    for (int it = 0; it < 4; ++it) {
      int c = it * 256 + tid;
      int row = c >> 3, j = c & 7;
      int src = ((j * 16) ^ ((row & 7) << 4)) >> 1;  // shorts
      gll16(A + (size_t)(m0 + row) * K + k0 + src, As[buf] + c * 8);
    }
#pragma unroll
    for (int it = 0; it < 4; ++it) {
      int c = it * 256 + tid;
      int row = c >> 3, j = c & 7;
      int src = ((j * 16) ^ ((row & 7) << 4)) >> 1;
      gll16(Bw + (size_t)(n0 + row) * K + k0 + src, Bs[buf] + c * 8);
    }
  };

  const int nt = K >> 6;
  stageAB(0, 0);
  __syncthreads();

  for (int t = 0; t < nt; ++t) {
    const int cur = t & 1;
    if (t + 1 < nt) stageAB((t + 1) << 6, cur ^ 1);  // prefetch next K-tile

#pragma unroll
    for (int ks = 0; ks < 2; ++ks) {
      bf16x8 af[4], bfr[4];
#pragma unroll
      for (int mt = 0; mt < 4; ++mt)
        af[mt] = ldswz(As[cur], wr * 64 + mt * 16 + r16, ks * 32 + g * 8);
#pragma unroll
      for (int nt2 = 0; nt2 < 4; ++nt2)
        bfr[nt2] = ldswz(Bs[cur], wc * 64 + nt2 * 16 + r16, ks * 32 + g * 8);
#pragma unroll
      for (int mt = 0; mt < 4; ++mt)
#pragma unroll
        for (int nt2 = 0; nt2 < 4; ++nt2)
          acc[mt][nt2] = MFMA16(af[mt], bfr[nt2], acc[mt][nt2]);
    }

    __syncthreads();  // drains vmcnt (next tile staged) + guards buffer reuse
  }

  // epilogue: C frag layout col = lane&15, row = (lane>>4)*4 + r
#pragma unroll
  for (int mt = 0; mt < 4; ++mt) {
#pragma unroll
    for (int nt2 = 0; nt2 < 4; ++nt2) {
#pragma unroll
      for (int r = 0; r < 4; ++r) {
        int m = m0 + wr * 64 + mt * 16 + g * 4 + r;
        int n = n0 + wc * 64 + nt2 * 16 + r16;
        float v = acc[mt][nt2][r];
        if (EPI == 0) {
          Cf[(size_t)m * N + n] = v;
        } else {
          int b = m >> 11, t2 = m & (ST - 1);
          int which = n >> 10, h = (n >> 6) & (SH - 1), d = n & (SD - 1);
          int bh = b * SH + h;
          if (which == 0)
            Qo[((size_t)bh * ST + t2) * SD + d] = f2bf(v * QSCALE);
          else if (which == 1)
            Ko[((size_t)bh * ST + t2) * SD + d] = f2bf(v);
          else
            VTo[((size_t)bh * SD + d) * ST + t2] = f2bf(v);
        }
      }
    }
  }
}

// ---- causal flash attention v6 (= v4 body + XCD-affinity remap) ------------
// QBLK=128 (4 waves x 32 q-cols), KVBLK=64, double-buffered K/V, XOR swizzle.
// 32x32x16 MFMA, swapped operands: S^T = mfma(K, Q). Softmax fully in-register;
// P redistributed to PV B-fragments via permlane32_swap (T12). exp2-domain,
// defer-max (T13). XCD-affinity: each XCD's co-resident blocks cover 8 heads
// (KV working set 4 MB = one L2), globally heavy-first.
// NOTE (R5 post-mortem): do NOT add accumulator state here — at
// __launch_bounds__(256,4) the VGPR budget is 128/wave and this body sits
// just under it; +20 VGPRs (ls_acc trick) caused 975 MB of scratch spill.

DEVI void stage_tile(const unsigned short* gbase, size_t rowstride,
                     unsigned short* lds, int tid) {
#pragma unroll
  for (int it = 0; it < 2; ++it) {
    int c = it * 256 + tid;
    int row = c >> 3, j = c & 7;
    int src = ((j * 16) ^ ((row & 7) << 4)) >> 1;  // shorts
    gll16(gbase + (size_t)row * rowstride + src, lds + c * 8);
  }
}

__global__ __launch_bounds__(256, 4) void attn_causal(
    const unsigned short* __restrict__ Q, const unsigned short* __restrict__ Kv,
    const unsigned short* __restrict__ VT, unsigned short* __restrict__ Y) {
  __shared__ unsigned short Ks[2][64 * 64];   // [t][d], swizzled
  __shared__ unsigned short Vs[2][64 * 64];   // [d][t], swizzled

  const int tid = threadIdx.x;
  const int lane = tid & 63;
  const int w = tid >> 6;
  const int l5 = lane & 31, h = lane >> 5;

  // XCD-affinity remap: xcd = lin&7 handles heads {xcd, xcd+8, ...};
  // qt descending -> all 64 heads' heaviest blocks dispatch first.
  const int lin = blockIdx.x + blockIdx.y * gridDim.x;  // 0..1023
  const int xcd = lin & 7;
  const int idx = lin >> 3;                 // 0..127
  const int qt = (ST / 128 - 1) - (idx >> 3);
  const int bh = xcd + 8 * (idx & 7);
  const size_t base = (size_t)bh * ST * SD;

  const int q_glob = qt * 128 + w * 32 + l5;   // this lane's q-row
  const int qwmin = qt * 128 + w * 32;         // wave q range [qwmin, qwmin+31]

  // Q B-fragments: col n = q = lane&31, k = h*8 + i, chained over kk (d-slices)
  bf16x8 qf[4];
#pragma unroll
  for (int kk = 0; kk < 4; ++kk)
    qf[kk] = ld8(Q + base + (size_t)q_glob * SD + kk * 16 + h * 8);

  float mrow = -__builtin_inff();
  float lrow = 0.f;
  f32x16 acc[2] = {};  // O^T: lane q=l5, d = dblk*32 + (reg&3) + 4h + 8*(reg>>2)

  const int nkv = 2 * qt + 2;
  stage_tile(Kv + base, SD, Ks[0], tid);
  stage_tile(VT + base, ST, Vs[0], tid);
  __syncthreads();

  for (int kvt = 0; kvt < nkv; ++kvt) {
    const int cur = kvt & 1;
    if (kvt + 1 < nkv) {  // prefetch next tile into other buffer
      stage_tile(Kv + base + (size_t)(kvt + 1) * 64 * SD, SD, Ks[cur ^ 1], tid);
      stage_tile(VT + base + (kvt + 1) * 64, ST, Vs[cur ^ 1], tid);
    }

    // tiles fully above this wave's q range contribute nothing
    const bool active = (kvt * 64) <= (qwmin + 31);
    if (active) {
      // S^T = K Q^T : two 32t x 32q blocks; lane owns q=l5, t-half per h
      f32x16 s0 = {}, s1 = {};
      __builtin_amdgcn_s_setprio(1);
#pragma unroll
      for (int kk = 0; kk < 4; ++kk) {
        bf16x8 k0 = ldswz(Ks[cur], l5, kk * 16 + h * 8);
        s0 = MFMA32(k0, qf[kk], s0);
      }
#pragma unroll
      for (int kk = 0; kk < 4; ++kk) {
        bf16x8 k1 = ldswz(Ks[cur], 32 + l5, kk * 16 + h * 8);
        s1 = MFMA32(k1, qf[kk], s1);
      }
      __builtin_amdgcn_s_setprio(0);

      if (kvt * 64 + 63 > qwmin) {  // diagonal overlap: causal mask
        const int t0 = kvt * 64 + 4 * h;
#pragma unroll
        for (int reg = 0; reg < 16; ++reg) {
          int t = t0 + (reg & 3) + 8 * (reg >> 2);
          if (t > q_glob) s0[reg] = -__builtin_inff();
          if (t + 32 > q_glob) s1[reg] = -__builtin_inff();
        }
      }

      // row max: elementwise + in-lane tree + one half-swap
      f32x16 mx;
#pragma unroll
      for (int i = 0; i < 16; ++i) mx[i] = fmaxf(s0[i], s1[i]);
#pragma unroll
      for (int i = 0; i < 8; ++i) mx[i] = fmaxf(mx[i], mx[i + 8]);
#pragma unroll
      for (int i = 0; i < 4; ++i) mx[i] = fmaxf(mx[i], mx[i + 4]);
      float bm = fmaxf(fmaxf(mx[0], mx[1]), fmaxf(mx[2], mx[3]));
      bm = swaphalf_max(bm);

      // defer-max: rescale only if running max grew by more than DMTHR
      if (__any(bm > mrow + DMTHR)) {
        float mn = fmaxf(mrow, bm);
        float corr = exp2f(mrow - mn);  // first tile: exp2(-inf)=0
        mrow = mn;
        lrow *= corr;
#pragma unroll
        for (int dblk = 0; dblk < 2; ++dblk)
#pragma unroll
          for (int i = 0; i < 16; ++i) acc[dblk][i] *= corr;
      }

      // P = exp2(S - m), in-lane sum + half-swap
#pragma unroll
      for (int i = 0; i < 16; ++i) {
        s0[i] = exp2f(s0[i] - mrow);
        s1[i] = exp2f(s1[i] - mrow);
      }
      f32x16 sm;
#pragma unroll
      for (int i = 0; i < 16; ++i) sm[i] = s0[i] + s1[i];
#pragma unroll
      for (int i = 0; i < 8; ++i) sm[i] += sm[i + 8];
#pragma unroll
      for (int i = 0; i < 4; ++i) sm[i] += sm[i + 4];
      float rs = (sm[0] + sm[1]) + (sm[2] + sm[3]);
      lrow += swaphalf_add(rs);

      // pack P -> bf16 PV B-fragments via permlane32_swap (no LDS roundtrip)
      bf16x8 pb[2][2];
      auto packblk = [&](const f32x16& S, bf16x8* out) {
        unsigned a = pkbf(S[0], S[1]), b2 = pkbf(S[2], S[3]);
        unsigned c = pkbf(S[4], S[5]), d2 = pkbf(S[6], S[7]);
        auto r0 = __builtin_amdgcn_permlane32_swap(a, c, false, false);
        auto r1 = __builtin_amdgcn_permlane32_swap(b2, d2, false, false);
        uint32x4v w0 = {(unsigned)r0[0], (unsigned)r1[0], (unsigned)r0[1], (unsigned)r1[1]};
        out[0] = __builtin_bit_cast(bf16x8, w0);
        unsigned e = pkbf(S[8], S[9]), f2 = pkbf(S[10], S[11]);
        unsigned g2 = pkbf(S[12], S[13]), h2 = pkbf(S[14], S[15]);
        auto r2 = __builtin_amdgcn_permlane32_swap(e, g2, false, false);
        auto r3 = __builtin_amdgcn_permlane32_swap(f2, h2, false, false);
        uint32x4v w1 = {(unsigned)r2[0], (unsigned)r3[0], (unsigned)r2[1], (unsigned)r3[1]};
        out[1] = __builtin_bit_cast(bf16x8, w1);
      };
      packblk(s0, pb[0]);
      packblk(s1, pb[1]);

      // O^T += V^T P^T : A = V^T (d rows), B = P^T (q cols)
      __builtin_amdgcn_s_setprio(1);
#pragma unroll
      for (int dblk = 0; dblk < 2; ++dblk)
#pragma unroll
        for (int tt = 0; tt < 2; ++tt)
#pragma unroll
          for (int sl = 0; sl < 2; ++sl) {
            bf16x8 va = ldswz(Vs[cur], dblk * 32 + l5, tt * 32 + sl * 16 + h * 8);
            acc[dblk] = MFMA32(va, pb[tt][sl], acc[dblk]);
          }
      __builtin_amdgcn_s_setprio(0);
    }

    __syncthreads();  // drains vmcnt (next tile staged) + guards buffer reuse
  }

  // epilogue: Y[B,T,E] bf16, e = head*64 + d; 4 consecutive d per reg-group
  const int b = bh >> 4, hd = bh & 15;
  const float inv = 1.f / lrow;
#pragma unroll
  for (int dblk = 0; dblk < 2; ++dblk)
#pragma unroll
    for (int rg = 0; rg < 4; ++rg) {
      bf16x4 o;
#pragma unroll
      for (int j = 0; j < 4; ++j) o[j] = (__bf16)(acc[dblk][rg * 4 + j] * inv);
      int d = dblk * 32 + rg * 8 + 4 * h;
      *(ushortx4*)&Y[((size_t)b * ST + q_glob) * SE + hd * SD + d] =
          __builtin_bit_cast(ushortx4, o);
    }
}

// ---- launch ----------------------------------------------------------------
extern "C" void kernel_launch(void* const* d_in, const int* in_sizes, int n_in,
                              void* d_out, int out_size, void* d_ws, size_t ws_size,
                              hipStream_t stream) {
  const float* x = (const float*)d_in[0];       // [4,2048,1024]
  const float* w_qkv = (const float*)d_in[1];   // [3072,1024]
  const float* w_out = (const float*)d_in[2];   // [1024,1024]
  float* out = (float*)d_out;                   // [4,2048,1024] f32

  const size_t NX = (size_t)SB * ST * SE;       // 8388608
  const size_t NQKV = (size_t)3 * SE * SE;      // 3145728
  const size_t NWO = (size_t)SE * SE;           // 1048576
  const size_t NHD = (size_t)SB * SH * ST * SD; // 8388608

  unsigned short* xb    = (unsigned short*)d_ws;        // 16MB, reused as Y later
  unsigned short* wqkvb = xb + NX;                      // 6MB
  unsigned short* woutb = wqkvb + NQKV;                 // 2MB
  unsigned short* q     = woutb + NWO;                  // 16MB
  unsigned short* k     = q + NHD;                      // 16MB
  unsigned short* vT    = k + NHD;                      // 16MB
  unsigned short* y     = xb;                           // alias (xb dead after GEMM1)

  cvt_f32_bf16<<<(int)(NX / 4 + 255) / 256, 256, 0, stream>>>(x, xb, (int)(NX / 4));
  cvt_f32_bf16<<<(int)(NQKV / 4 + 255) / 256, 256, 0, stream>>>(w_qkv, wqkvb, (int)(NQKV / 4));
  cvt_f32_bf16<<<(int)(NWO / 4 + 255) / 256, 256, 0, stream>>>(w_out, woutb, (int)(NWO / 4));

  // qkv = x @ w_qkv^T, scattered into Q/K/VT
  gemm_nt<1><<<dim3(3 * SE / 128, SB * ST / 128), 256, 0, stream>>>(
      xb, wqkvb, nullptr, q, k, vT, SB * ST, 3 * SE, SE);

  attn_causal<<<dim3(ST / 128, SB * SH), 256, 0, stream>>>(q, k, vT, y);

  // out = y @ w_out^T (f32 out)
  gemm_nt<0><<<dim3(SE / 128, SB * ST / 128), 256, 0, stream>>>(
      y, woutb, out, nullptr, nullptr, nullptr, SB * ST, SE, SE);
}